// Round 1
// baseline (345.738 us; speedup 1.0000x reference)
//
#include <hip/hip_runtime.h>
#include <cstdint>
#include <cstddef>

#define B_ROWS 8192
#define IN_DIM 2048
#define HIDDEN 2048
#define FAN    4096
#define NJ     32          // 4 gates x 8 wires
#define SUB    64          // k-subtile staged in LDS
#define PITCH  65          // +1 pad: conflict-free column reads
#define WAVES_P1 2
#define TPB_P1 (WAVES_P1 * 64)          // 128 threads
#define ROWS_PER_BLOCK (WAVES_P1 * 64)  // 128 rows

// ---------------- Pass 1: partial dot products ----------------
// grid = 64 rowblocks * KC kchunks; block = 128 (2 waves, lane = row)
// Spart layout: [KC][NJ][B_ROWS]
extern "C" __global__ __launch_bounds__(TPB_P1, 2)
void p1_gemv(const float* __restrict__ x, const float* __restrict__ hx,
             const float* __restrict__ Wf, const float* __restrict__ Wi,
             const float* __restrict__ Wg, const float* __restrict__ Wo,
             float* __restrict__ Spart, int KC, int CHUNK)
{
    __shared__ float A[WAVES_P1][64][PITCH];   // 33,280 B

    const int bid    = blockIdx.x;
    const int kc     = bid % KC;
    const int rowblk = bid / KC;
    const int tid    = threadIdx.x;
    const int wave   = tid >> 6;
    const int lane   = tid & 63;
    const int row    = rowblk * ROWS_PER_BLOCK + wave * 64 + lane;
    const int k0     = kc * CHUNK;

    float acc[NJ];
#pragma unroll
    for (int j = 0; j < NJ; ++j) acc[j] = 0.f;

    const int r4 = lane >> 4;          // 0..3
    const int c4 = (lane & 15) << 2;   // 0,4,...,60
    const int stage_row0 = rowblk * ROWS_PER_BLOCK + wave * 64;

    const int nsub = CHUNK >> 6;       // CHUNK / SUB
    for (int s = 0; s < nsub; ++s) {
        const int ks = k0 + s * SUB;
        // ---- stage this wave's 64 rows x 64 cols (coalesced float4) ----
        const int kk = ks + c4;        // subtile never straddles the x|hx boundary
        const float* srcp = (kk < IN_DIM)
            ? (x  + (size_t)stage_row0 * IN_DIM + kk)
            : (hx + (size_t)stage_row0 * HIDDEN + (kk - IN_DIM));
#pragma unroll
        for (int p = 0; p < 16; ++p) {
            const int r = (p << 2) + r4;
            float4 v = *reinterpret_cast<const float4*>(srcp + (size_t)r * 2048);
            A[wave][r][c4 + 0] = v.x;
            A[wave][r][c4 + 1] = v.y;
            A[wave][r][c4 + 2] = v.z;
            A[wave][r][c4 + 3] = v.w;
        }
        __syncthreads();   // cross-lane LDS visibility within the wave/block

        // ---- my row into registers ----
        float a[SUB];
#pragma unroll
        for (int k = 0; k < SUB; ++k) a[k] = A[wave][lane][k];

        // ---- 32 dot-accumulators; weights are wave-uniform -> s_load ----
        const float* Ws[4] = {Wf, Wi, Wg, Wo};
#pragma unroll
        for (int g = 0; g < 4; ++g) {
#pragma unroll
            for (int w = 0; w < 8; ++w) {
                const float* wp = Ws[g] + (size_t)w * FAN + ks;
                float sum = acc[g * 8 + w];
#pragma unroll
                for (int k = 0; k < SUB; ++k) sum = fmaf(a[k], wp[k], sum);
                acc[g * 8 + w] = sum;
            }
        }
        __syncthreads();   // keep waves/staging in lockstep before overwrite
    }

    // ---- write partials, coalesced across lanes per j ----
    float* sp = Spart + (size_t)kc * NJ * B_ROWS + row;
#pragma unroll
    for (int j = 0; j < NJ; ++j) sp[(size_t)j * B_ROWS] = acc[j];
}

// ---------------- Pass 2: sum partials, cos, reduce to q[4] ----------------
// grid = 64 blocks * 128 threads = 8192 threads (one per row)
extern "C" __global__ __launch_bounds__(128)
void p2_cos_reduce(const float* __restrict__ Spart,
                   const float* __restrict__ bf, const float* __restrict__ bi,
                   const float* __restrict__ bg, const float* __restrict__ bo,
                   float* __restrict__ q, int KC)
{
    const int row = blockIdx.x * 128 + threadIdx.x;   // 0..8191
    const float* Bs[4] = {bf, bi, bg, bo};
    float ag[4];
#pragma unroll
    for (int g = 0; g < 4; ++g) {
        float gacc = 0.f;
#pragma unroll
        for (int w = 0; w < 8; ++w) {
            const int j = g * 8 + w;
            float s = 0.f;
            for (int kc = 0; kc < KC; ++kc)
                s += Spart[((size_t)kc * NJ + j) * B_ROWS + row];
            gacc += cosf(s + Bs[g][w]);
        }
        ag[g] = gacc;
    }
    // wave-level reduce (64 lanes), then one atomic per wave per gate
#pragma unroll
    for (int g = 0; g < 4; ++g) {
#pragma unroll
        for (int off = 32; off > 0; off >>= 1)
            ag[g] += __shfl_down(ag[g], off, 64);
    }
    if ((threadIdx.x & 63) == 0) {
#pragma unroll
        for (int g = 0; g < 4; ++g) atomicAdd(&q[g], ag[g]);
    }
}

// ---------------- Pass 3: elementwise LSTM update ----------------
extern "C" __global__ __launch_bounds__(256)
void p3_elementwise(const float* __restrict__ cx, const float* __restrict__ q,
                    float* __restrict__ out)
{
    const float qf = q[0], qi = q[1], qg = q[2], qo = q[3];
    const float f  = 1.f / (1.f + expf(-qf));
    const float ii = 1.f / (1.f + expf(-qi));
    const float g  = tanhf(qg);
    const float o  = 1.f / (1.f + expf(-qo));
    const float ig = ii * g;

    const size_t N  = (size_t)B_ROWS * HIDDEN;     // 16,777,216
    const size_t N4 = N >> 2;                      // 4,194,304 float4s
    const float4* cx4  = (const float4*)cx;
    float4* outh = (float4*)out;
    float4* outc = (float4*)(out + N);

    for (size_t idx = (size_t)blockIdx.x * blockDim.x + threadIdx.x; idx < N4;
         idx += (size_t)gridDim.x * blockDim.x) {
        float4 c = cx4[idx];
        float4 cn, hn;
        cn.x = fmaf(f, c.x, ig);
        cn.y = fmaf(f, c.y, ig);
        cn.z = fmaf(f, c.z, ig);
        cn.w = fmaf(f, c.w, ig);
        hn.x = o * tanhf(cn.x);
        hn.y = o * tanhf(cn.y);
        hn.z = o * tanhf(cn.z);
        hn.w = o * tanhf(cn.w);
        outc[idx] = cn;
        outh[idx] = hn;
    }
}

// ---------------- launcher ----------------
extern "C" void kernel_launch(void* const* d_in, const int* in_sizes, int n_in,
                              void* d_out, int out_size, void* d_ws, size_t ws_size,
                              hipStream_t stream)
{
    const float* x  = (const float*)d_in[0];
    const float* hx = (const float*)d_in[1];
    const float* cx = (const float*)d_in[2];
    const float* Wf = (const float*)d_in[3];
    const float* bf = (const float*)d_in[4];
    const float* Wi = (const float*)d_in[5];
    const float* bi = (const float*)d_in[6];
    const float* Wg = (const float*)d_in[7];
    const float* bg = (const float*)d_in[8];
    const float* Wo = (const float*)d_in[9];
    const float* bo = (const float*)d_in[10];
    float* out = (float*)d_out;

    // Pick the largest K-split whose partial buffer fits the workspace.
    int KC = 16;
    while (KC > 1 &&
           ((size_t)KC * NJ * B_ROWS + 4) * sizeof(float) > ws_size)
        KC >>= 1;
    const int CHUNK = FAN / KC;

    float* Spart = (float*)d_ws;
    float* q     = Spart + (size_t)KC * NJ * B_ROWS;

    // q must be zeroed on every call (graph replays don't re-poison ws)
    hipMemsetAsync(q, 0, 4 * sizeof(float), stream);

    p1_gemv<<<dim3(64 * KC), dim3(TPB_P1), 0, stream>>>(
        x, hx, Wf, Wi, Wg, Wo, Spart, KC, CHUNK);
    p2_cos_reduce<<<dim3(64), dim3(128), 0, stream>>>(
        Spart, bf, bi, bg, bo, q, KC);
    p3_elementwise<<<dim3(2048), dim3(256), 0, stream>>>(cx, q, out);
}

// Round 2
// 93.837 us; speedup vs baseline: 3.6844x; 3.6844x over previous
//
#include <hip/hip_runtime.h>
#include <hip/hip_bf16.h>
#include <cstdint>
#include <cstddef>

#define B_ROWS 8192
#define KDIM   4096
#define IN_DIM 2048
#define HIDDEN 2048
#define NJ     32          // 4 gates x 8 wires
#define KC     8           // K-split
#define CHUNK  (KDIM / KC) // 512
#define KSTEPS (CHUNK / 32)// 16 MFMA K-steps per wave

typedef __bf16 bf16x8 __attribute__((ext_vector_type(8)));
typedef float  f32x4  __attribute__((ext_vector_type(4)));

// ---------------- Pass 0: pack weights to bf16 [32][4096] ----------------
extern "C" __global__ __launch_bounds__(256)
void w_pack(const float* __restrict__ Wf, const float* __restrict__ Wi,
            const float* __restrict__ Wg, const float* __restrict__ Wo,
            __bf16* __restrict__ Wb)
{
    int idx = blockIdx.x * 256 + threadIdx.x;      // 0 .. 131071
    if (idx >= NJ * KDIM) return;
    int j = idx >> 12;                             // / 4096
    int k = idx & (KDIM - 1);
    const float* W = (j < 8) ? Wf : (j < 16) ? Wi : (j < 24) ? Wg : Wo;
    Wb[idx] = (__bf16)W[(size_t)(j & 7) * KDIM + k];
}

// ---------------- Pass 1: split-K MFMA GEMM ----------------
// grid = 128 mblocks * 8 kc ; block = 256 (4 waves, each wave = 16 rows)
// Spart layout: [KC][B_ROWS][NJ]
extern "C" __global__ __launch_bounds__(256)
void p1_mfma(const float* __restrict__ x, const float* __restrict__ hx,
             const __bf16* __restrict__ Wb, float* __restrict__ Spart)
{
    const int bid  = blockIdx.x;
    const int kc   = bid & (KC - 1);
    const int mb   = bid >> 3;                     // 0..127
    const int wave = threadIdx.x >> 6;
    const int lane = threadIdx.x & 63;
    const int row0 = (mb * 4 + wave) * 16;
    const int k0   = kc * CHUNK;

    const int lrow = lane & 15;                    // A row / B col within frag
    const int koff = (lane >> 4) * 8;              // 8 consecutive k per lane

    // A source: chunk lies entirely in x (kc<4) or hx (kc>=4); row stride 2048
    const float* Abase = (kc < 4)
        ? (x  + (size_t)(row0 + lrow) * IN_DIM + (k0 + koff))
        : (hx + (size_t)(row0 + lrow) * HIDDEN + (k0 - IN_DIM + koff));
    const __bf16* Bbase = Wb + (size_t)lrow * KDIM + k0 + koff;

    f32x4 acc0 = {0.f, 0.f, 0.f, 0.f};
    f32x4 acc1 = {0.f, 0.f, 0.f, 0.f};

#pragma unroll 4
    for (int s = 0; s < KSTEPS; ++s) {
        const float* ap = Abase + s * 32;
        float4 a0 = *reinterpret_cast<const float4*>(ap);
        float4 a1 = *reinterpret_cast<const float4*>(ap + 4);
        bf16x8 af;
        af[0] = (__bf16)a0.x; af[1] = (__bf16)a0.y;
        af[2] = (__bf16)a0.z; af[3] = (__bf16)a0.w;
        af[4] = (__bf16)a1.x; af[5] = (__bf16)a1.y;
        af[6] = (__bf16)a1.z; af[7] = (__bf16)a1.w;

        bf16x8 b0 = *reinterpret_cast<const bf16x8*>(Bbase + (size_t)s * 32);
        bf16x8 b1 = *reinterpret_cast<const bf16x8*>(Bbase + (size_t)16 * KDIM + (size_t)s * 32);

        acc0 = __builtin_amdgcn_mfma_f32_16x16x32_bf16(af, b0, acc0, 0, 0, 0);
        acc1 = __builtin_amdgcn_mfma_f32_16x16x32_bf16(af, b1, acc1, 0, 0, 0);
    }

    // D layout (16x16x32): n = lane&15, m = (lane>>4)*4 + reg
    float* sp = Spart + ((size_t)kc * B_ROWS + row0) * NJ;
    const int m0 = (lane >> 4) * 4;
#pragma unroll
    for (int r = 0; r < 4; ++r) {
        sp[(size_t)(m0 + r) * NJ + lrow]      = acc0[r];
        sp[(size_t)(m0 + r) * NJ + 16 + lrow] = acc1[r];
    }
}

// ---------------- Pass 2: sum partials, bias, cos, reduce to q[4] ----------
// grid = 64 blocks * 256 threads = 16384 threads; each thread: 16 (row,j) pairs
extern "C" __global__ __launch_bounds__(256)
void p2_cos_reduce(const float* __restrict__ Spart,
                   const float* __restrict__ bf, const float* __restrict__ bi,
                   const float* __restrict__ bg, const float* __restrict__ bo,
                   float* __restrict__ q)
{
    __shared__ float ql[4];
    if (threadIdx.x < 4) ql[threadIdx.x] = 0.f;
    __syncthreads();

    const int t    = blockIdx.x * 256 + threadIdx.x;  // 0..16383
    const int j    = t & 31;                          // constant per thread
    const int gate = j >> 3;
    const float* Bp = (gate == 0) ? bf : (gate == 1) ? bi : (gate == 2) ? bg : bo;
    const float bj = Bp[j & 7];

    float accg = 0.f;
#pragma unroll
    for (int i = 0; i < 16; ++i) {
        const int row = (t >> 5) + i * 512;
        float s = 0.f;
#pragma unroll
        for (int kc = 0; kc < KC; ++kc)
            s += Spart[((size_t)kc * B_ROWS + row) * NJ + j];
        accg += cosf(s + bj);
    }

    // 8-lane group reduce (lanes in a group share the same gate)
    accg += __shfl_xor(accg, 1, 64);
    accg += __shfl_xor(accg, 2, 64);
    accg += __shfl_xor(accg, 4, 64);
    if ((threadIdx.x & 7) == 0) atomicAdd(&ql[gate], accg);
    __syncthreads();
    if (threadIdx.x < 4) atomicAdd(&q[threadIdx.x], ql[threadIdx.x]);
}

// ---------------- Pass 3: elementwise LSTM update ----------------
extern "C" __global__ __launch_bounds__(256)
void p3_elementwise(const float* __restrict__ cx, const float* __restrict__ q,
                    float* __restrict__ out)
{
    const float qf = q[0], qi = q[1], qg = q[2], qo = q[3];
    const float f  = 1.f / (1.f + expf(-qf));
    const float ii = 1.f / (1.f + expf(-qi));
    const float g  = tanhf(qg);
    const float o  = 1.f / (1.f + expf(-qo));
    const float ig = ii * g;

    const size_t N  = (size_t)B_ROWS * HIDDEN;     // 16,777,216
    const size_t N4 = N >> 2;
    const float4* cx4 = (const float4*)cx;
    float4* outh = (float4*)out;
    float4* outc = (float4*)(out + N);

    for (size_t idx = (size_t)blockIdx.x * blockDim.x + threadIdx.x; idx < N4;
         idx += (size_t)gridDim.x * blockDim.x) {
        float4 c = cx4[idx];
        float4 cn, hn;
        cn.x = fmaf(f, c.x, ig);
        cn.y = fmaf(f, c.y, ig);
        cn.z = fmaf(f, c.z, ig);
        cn.w = fmaf(f, c.w, ig);
        hn.x = o * tanhf(cn.x);
        hn.y = o * tanhf(cn.y);
        hn.z = o * tanhf(cn.z);
        hn.w = o * tanhf(cn.w);
        outc[idx] = cn;
        outh[idx] = hn;
    }
}

// ---------------- launcher ----------------
extern "C" void kernel_launch(void* const* d_in, const int* in_sizes, int n_in,
                              void* d_out, int out_size, void* d_ws, size_t ws_size,
                              hipStream_t stream)
{
    const float* x  = (const float*)d_in[0];
    const float* hx = (const float*)d_in[1];
    const float* cx = (const float*)d_in[2];
    const float* Wf = (const float*)d_in[3];
    const float* bf = (const float*)d_in[4];
    const float* Wi = (const float*)d_in[5];
    const float* bi = (const float*)d_in[6];
    const float* Wg = (const float*)d_in[7];
    const float* bg = (const float*)d_in[8];
    const float* Wo = (const float*)d_in[9];
    const float* bo = (const float*)d_in[10];
    float* out = (float*)d_out;

    // ws layout: Spart [KC][8192][32] f32 (8 MB) | Wb [32][4096] bf16 (256 KB) | q[4]
    float*   Spart = (float*)d_ws;
    __bf16*  Wb    = (__bf16*)(Spart + (size_t)KC * B_ROWS * NJ);
    float*   q     = (float*)(Wb + (size_t)NJ * KDIM);

    // q accumulators must be zeroed every call (atomics accumulate into them)
    hipMemsetAsync(q, 0, 4 * sizeof(float), stream);

    w_pack<<<dim3((NJ * KDIM + 255) / 256), dim3(256), 0, stream>>>(Wf, Wi, Wg, Wo, Wb);
    p1_mfma<<<dim3(128 * KC), dim3(256), 0, stream>>>(x, hx, Wb, Spart);
    p2_cos_reduce<<<dim3(64), dim3(256), 0, stream>>>(Spart, bf, bi, bg, bo, q);
    p3_elementwise<<<dim3(2048), dim3(256), 0, stream>>>(cx, q, out);
}

// Round 4
// 91.329 us; speedup vs baseline: 3.7856x; 1.0275x over previous
//
#include <hip/hip_runtime.h>
#include <hip/hip_bf16.h>
#include <cstdint>
#include <cstddef>

#define B_ROWS 8192
#define KDIM   4096
#define IN_DIM 2048
#define HIDDEN 2048
#define NJ     32          // 4 gates x 8 wires
#define KC     8           // K-split
#define CHUNK  (KDIM / KC) // 512
#define KSTEPS (CHUNK / 32)// 16 MFMA K-steps per wave

typedef __bf16 bf16x8 __attribute__((ext_vector_type(8)));
typedef float  f32x4  __attribute__((ext_vector_type(4)));

// ---------------- Pass 0: pack weights to bf16 [32][4096]; zero q ---------
// grid = 128 blocks * 256 thr; each thread converts 4 consecutive floats
extern "C" __global__ __launch_bounds__(256)
void w_pack(const float* __restrict__ Wf, const float* __restrict__ Wi,
            const float* __restrict__ Wg, const float* __restrict__ Wo,
            __bf16* __restrict__ Wb, float* __restrict__ q)
{
    if (blockIdx.x == 0 && threadIdx.x < 4) q[threadIdx.x] = 0.f;

    const int t    = blockIdx.x * 256 + threadIdx.x;   // 0 .. 32767
    const int idx4 = t << 2;                           // element index, x4
    const int j    = idx4 >> 12;                       // / 4096
    const int k    = idx4 & (KDIM - 1);
    const float* W = (j < 8) ? Wf : (j < 16) ? Wi : (j < 24) ? Wg : Wo;
    f32x4 v = *reinterpret_cast<const f32x4*>(W + (size_t)(j & 7) * KDIM + k);
    __bf16 tmp[4] = {(__bf16)v.x, (__bf16)v.y, (__bf16)v.z, (__bf16)v.w};
    *reinterpret_cast<uint2*>(Wb + idx4) = *reinterpret_cast<const uint2*>(tmp);
}

// ---------------- Pass 1: split-K MFMA GEMM ----------------
// grid = 128 mblocks * 8 kc ; block = 256 (4 waves, each wave = 16 rows)
// Spart layout: [KC][B_ROWS][NJ]
extern "C" __global__ __launch_bounds__(256)
void p1_mfma(const float* __restrict__ x, const float* __restrict__ hx,
             const __bf16* __restrict__ Wb, float* __restrict__ Spart)
{
    const int bid  = blockIdx.x;
    const int kc   = bid & (KC - 1);
    const int mb   = bid >> 3;                     // 0..127
    const int wave = threadIdx.x >> 6;
    const int lane = threadIdx.x & 63;
    const int row0 = (mb * 4 + wave) * 16;
    const int k0   = kc * CHUNK;

    const int lrow = lane & 15;                    // A row / B col within frag
    const int koff = (lane >> 4) * 8;              // 8 consecutive k per lane

    // A source: chunk lies entirely in x (kc<4) or hx (kc>=4); row stride 2048
    const float* Abase = (kc < 4)
        ? (x  + (size_t)(row0 + lrow) * IN_DIM + (k0 + koff))
        : (hx + (size_t)(row0 + lrow) * HIDDEN + (k0 - IN_DIM + koff));
    const __bf16* Bbase = Wb + (size_t)lrow * KDIM + k0 + koff;

    f32x4 acc0 = {0.f, 0.f, 0.f, 0.f};
    f32x4 acc1 = {0.f, 0.f, 0.f, 0.f};

#pragma unroll 4
    for (int s = 0; s < KSTEPS; ++s) {
        const float* ap = Abase + s * 32;
        // streaming A: no reuse -> non-temporal, keep L3 for output/Spart
        f32x4 a0 = __builtin_nontemporal_load(reinterpret_cast<const f32x4*>(ap));
        f32x4 a1 = __builtin_nontemporal_load(reinterpret_cast<const f32x4*>(ap) + 1);
        bf16x8 af;
        af[0] = (__bf16)a0.x; af[1] = (__bf16)a0.y;
        af[2] = (__bf16)a0.z; af[3] = (__bf16)a0.w;
        af[4] = (__bf16)a1.x; af[5] = (__bf16)a1.y;
        af[6] = (__bf16)a1.z; af[7] = (__bf16)a1.w;

        bf16x8 b0 = *reinterpret_cast<const bf16x8*>(Bbase + (size_t)s * 32);
        bf16x8 b1 = *reinterpret_cast<const bf16x8*>(Bbase + (size_t)16 * KDIM + (size_t)s * 32);

        acc0 = __builtin_amdgcn_mfma_f32_16x16x32_bf16(af, b0, acc0, 0, 0, 0);
        acc1 = __builtin_amdgcn_mfma_f32_16x16x32_bf16(af, b1, acc1, 0, 0, 0);
    }

    // D layout (16x16x32): n = lane&15, m = (lane>>4)*4 + reg
    float* sp = Spart + ((size_t)kc * B_ROWS + row0) * NJ;
    const int m0 = (lane >> 4) * 4;
#pragma unroll
    for (int r = 0; r < 4; ++r) {
        sp[(size_t)(m0 + r) * NJ + lrow]      = acc0[r];
        sp[(size_t)(m0 + r) * NJ + 16 + lrow] = acc1[r];
    }
}

// ---------------- Pass 2: sum partials, bias, cos, reduce to q[4] ----------
// grid = 256 blocks * 256 thr = 65536 threads; each thread: 4 (row,j) pairs
extern "C" __global__ __launch_bounds__(256)
void p2_cos_reduce(const float* __restrict__ Spart,
                   const float* __restrict__ bf, const float* __restrict__ bi,
                   const float* __restrict__ bg, const float* __restrict__ bo,
                   float* __restrict__ q)
{
    __shared__ float ql[4];
    if (threadIdx.x < 4) ql[threadIdx.x] = 0.f;
    __syncthreads();

    const int t    = blockIdx.x * 256 + threadIdx.x;  // 0..65535
    const int j    = t & 31;                          // constant per thread
    const int gate = j >> 3;
    const float* Bp = (gate == 0) ? bf : (gate == 1) ? bi : (gate == 2) ? bg : bo;
    const float bj = Bp[j & 7];

    float accg = 0.f;
#pragma unroll
    for (int i = 0; i < 4; ++i) {
        const int row = (t >> 5) + i * 2048;
        float s = 0.f;
#pragma unroll
        for (int kc = 0; kc < KC; ++kc)
            s += Spart[((size_t)kc * B_ROWS + row) * NJ + j];
        accg += cosf(s + bj);
    }

    // 8-lane group reduce (lanes in a group share the same gate)
    accg += __shfl_xor(accg, 1, 64);
    accg += __shfl_xor(accg, 2, 64);
    accg += __shfl_xor(accg, 4, 64);
    if ((threadIdx.x & 7) == 0) atomicAdd(&ql[gate], accg);
    __syncthreads();
    if (threadIdx.x < 4) atomicAdd(&q[threadIdx.x], ql[threadIdx.x]);
}

// ---------------- Pass 3: elementwise LSTM update ----------------
extern "C" __global__ __launch_bounds__(256)
void p3_elementwise(const float* __restrict__ cx, const float* __restrict__ q,
                    float* __restrict__ out)
{
    const float qf = q[0], qi = q[1], qg = q[2], qo = q[3];
    const float f  = 1.f / (1.f + expf(-qf));
    const float ii = 1.f / (1.f + expf(-qi));
    const float g  = tanhf(qg);
    const float o  = 1.f / (1.f + expf(-qo));
    const float ig = ii * g;

    const size_t N  = (size_t)B_ROWS * HIDDEN;     // 16,777,216
    const size_t N4 = N >> 2;
    const f32x4* cx4 = (const f32x4*)cx;
    f32x4* outh = (f32x4*)out;
    f32x4* outc = (f32x4*)(out + N);

    for (size_t idx = (size_t)blockIdx.x * blockDim.x + threadIdx.x; idx < N4;
         idx += (size_t)gridDim.x * blockDim.x) {
        f32x4 c = __builtin_nontemporal_load(cx4 + idx);  // streaming, no reuse
        f32x4 cn, hn;
        cn.x = fmaf(f, c.x, ig);
        cn.y = fmaf(f, c.y, ig);
        cn.z = fmaf(f, c.z, ig);
        cn.w = fmaf(f, c.w, ig);
        hn.x = o * tanhf(cn.x);
        hn.y = o * tanhf(cn.y);
        hn.z = o * tanhf(cn.z);
        hn.w = o * tanhf(cn.w);
        outc[idx] = cn;
        outh[idx] = hn;
    }
}

// ---------------- launcher ----------------
extern "C" void kernel_launch(void* const* d_in, const int* in_sizes, int n_in,
                              void* d_out, int out_size, void* d_ws, size_t ws_size,
                              hipStream_t stream)
{
    const float* x  = (const float*)d_in[0];
    const float* hx = (const float*)d_in[1];
    const float* cx = (const float*)d_in[2];
    const float* Wf = (const float*)d_in[3];
    const float* bf = (const float*)d_in[4];
    const float* Wi = (const float*)d_in[5];
    const float* bi = (const float*)d_in[6];
    const float* Wg = (const float*)d_in[7];
    const float* bg = (const float*)d_in[8];
    const float* Wo = (const float*)d_in[9];
    const float* bo = (const float*)d_in[10];
    float* out = (float*)d_out;

    // ws layout: Spart [KC][8192][32] f32 (8 MB) | Wb [32][4096] bf16 (256 KB) | q[4]
    float*   Spart = (float*)d_ws;
    __bf16*  Wb    = (__bf16*)(Spart + (size_t)KC * B_ROWS * NJ);
    float*   q     = (float*)(Wb + (size_t)NJ * KDIM);

    w_pack<<<dim3(128), dim3(256), 0, stream>>>(Wf, Wi, Wg, Wo, Wb, q);
    p1_mfma<<<dim3(128 * KC), dim3(256), 0, stream>>>(x, hx, Wb, Spart);
    p2_cos_reduce<<<dim3(256), dim3(256), 0, stream>>>(Spart, bf, bi, bg, bo, q);
    p3_elementwise<<<dim3(2048), dim3(256), 0, stream>>>(cx, q, out);
}